// Round 2
// baseline (509.554 us; speedup 1.0000x reference)
//
#include <hip/hip_runtime.h>

#define DM 4096
#define NE 64
#define NTOK 16384

// out = [top2 weights (16384*2) | top2 indices as f32 (16384*2) | aux_loss]
// ws  = [Wt (4096*64 f32) | acc64 (64 f32)]

__global__ __launch_bounds__(256) void prep_kernel(const float* __restrict__ W,
                                                   float* __restrict__ Wt,
                                                   float* __restrict__ acc64) {
  int idx = blockIdx.x * 256 + threadIdx.x;   // (e,k), coalesced read
  int e = idx >> 12;
  int k = idx & 4095;
  Wt[k * 64 + e] = W[idx];
  if (idx < 64) acc64[idx] = 0.0f;
}

typedef __attribute__((address_space(3))) char lds_char;
typedef const __attribute__((address_space(1))) char glb_char;

__device__ __forceinline__ void gload_lds16(const float* g, char* l) {
  __builtin_amdgcn_global_load_lds((glb_char*)g, (lds_char*)l, 16, 0, 0);
}

__global__ __launch_bounds__(512, 2) void router_main(const float* __restrict__ x,
                                                      const float* __restrict__ Wt,
                                                      float* __restrict__ out,
                                                      float* __restrict__ acc64) {
  // smem union: main loop = x tiles [2 streams][2 bufs][64 tok][16 chunks(16B)]
  //             epilogue  = lg[64][65] logits
  __shared__ char smem[65536];
  const int tid = threadIdx.x;
  const int lane = tid & 63;                  // = token within block
  const int w = tid >> 6;                     // wave 0..7
  const int eg = w >> 1;                      // expert group: experts [16eg,16eg+16)
  const int kh = w & 1;                       // K half: k in [2048*kh, 2048*kh+2048)
  const int tb = blockIdx.x * 64;

  // ---- staging setup: thread stages chunks {tid, tid+512} of both streams ----
  // chunk f: token t=f>>4, slot cc=f&15 holds k-chunk c=cc^(t&7) (XOR swizzle,
  // pre-swizzled GLOBAL source + linear LDS dest, per m104/m173)
  const int f0 = tid, f1 = tid + 512;
  const int st0 = f0 >> 4, sc0 = (f0 & 15) ^ (st0 & 7);
  const int st1 = f1 >> 4, sc1 = (f1 & 15) ^ (st1 & 7);
  const float* g00 = x + (size_t)(tb + st0) * DM + sc0 * 4;          // stream 0
  const float* g01 = x + (size_t)(tb + st1) * DM + sc1 * 4;
  const float* g10 = g00 + 2048;                                     // stream 1
  const float* g11 = g01 + 2048;
  char* lbase = smem + (size_t)(w * 64) * 16;  // wave-uniform LDS base (+lane*16 by HW)

  // ---- W pipeline: 16 float4 (4k x 16e) per iter, 2-deep ping-pong in VGPRs ----
  int wb = kh * 2048 * 16 + eg * 4;            // float4 index of (k=2048*kh, je=0)
  asm volatile("" : "+v"(wb));                 // pin to VGPR: force VMEM, not s_load
  const float4* wt4 = (const float4*)Wt;

  float acc[16];
#pragma unroll
  for (int e = 0; e < 16; ++e) acc[e] = 0.0f;

  float4 wreg[2][16];
#pragma unroll
  for (int q = 0; q < 16; ++q)                 // preload j=0
    wreg[0][q] = wt4[wb + (q >> 2) * 16 + (q & 3)];

  // prologue: stage tile 0, both streams, buf 0
  gload_lds16(g00, lbase + 0 * 16384);
  gload_lds16(g01, lbase + 0 * 16384 + 512 * 16);
  gload_lds16(g10, lbase + 2 * 16384);
  gload_lds16(g11, lbase + 2 * 16384 + 512 * 16);
  __syncthreads();

  const int t7 = lane & 7;
  const int xrow = lane << 8;                  // lane's row byte offset in a stream-buf

  int buf = 0;
  for (int ts = 0; ts < 32; ++ts) {
    const char* xbase = smem + (kh * 2 + buf) * 16384 + xrow;
#pragma unroll 4
    for (int i = 0; i < 16; ++i) {
      const int j = ts * 16 + i;
      // issue next-tile staging AFTER iter 0 so W waits never include staging
      if (i == 1 && ts + 1 < 32) {
        const int nb = buf ^ 1;
        const int off = (ts + 1) * 64;
        gload_lds16(g00 + off, lbase + nb * 16384);
        gload_lds16(g01 + off, lbase + nb * 16384 + 512 * 16);
        gload_lds16(g10 + off, lbase + (2 + nb) * 16384);
        gload_lds16(g11 + off, lbase + (2 + nb) * 16384 + 512 * 16);
      }
      float4 xv = *(const float4*)(xbase + ((i ^ t7) << 4));  // conflict-free b128
      const int p = i & 1;                     // static under unroll (16 even)
      const int jn = (j + 1) & 511;            // wrap avoids OOB on last iter
#pragma unroll
      for (int q = 0; q < 16; ++q)             // prefetch W for j+1
        wreg[p ^ 1][q] = wt4[wb + 64 * jn + (q >> 2) * 16 + (q & 3)];
#pragma unroll
      for (int jk = 0; jk < 4; ++jk) {
        const float xk = (&xv.x)[jk];
#pragma unroll
        for (int je = 0; je < 4; ++je) {
          const float4 wv = wreg[p][jk * 4 + je];
          acc[je * 4 + 0] = fmaf(xk, wv.x, acc[je * 4 + 0]);
          acc[je * 4 + 1] = fmaf(xk, wv.y, acc[je * 4 + 1]);
          acc[je * 4 + 2] = fmaf(xk, wv.z, acc[je * 4 + 2]);
          acc[je * 4 + 3] = fmaf(xk, wv.w, acc[je * 4 + 3]);
        }
      }
    }
    __syncthreads();                           // drains vmcnt: next buf ready
    buf ^= 1;
  }

  // ---- epilogue: smem becomes lg[64][65] ----
  float (*lg)[65] = (float (*)[65])smem;
  float* lgf = (float*)smem;
  for (int i2 = tid; i2 < 64 * 65; i2 += 512) lgf[i2] = 0.0f;
  __syncthreads();
#pragma unroll
  for (int e = 0; e < 16; ++e)
    atomicAdd(&lg[lane][eg * 16 + e], acc[e]); // 2 contributions/cell (kh halves)
  __syncthreads();

  if (w == 0) {
    const int token = tb + lane;
    float l[64];
    float m1 = -3.4e38f, m2 = -3.4e38f;
    int i1 = 0, i2 = 0;
#pragma unroll
    for (int e = 0; e < 64; ++e) {
      float v = lg[lane][e];
      l[e] = v;
      if (v > m1) { m2 = m1; i2 = i1; m1 = v; i1 = e; }   // strict > = lax.top_k order
      else if (v > m2) { m2 = v; i2 = e; }
    }
    float den = 0.0f;
#pragma unroll
    for (int e = 0; e < 64; ++e) {
      float p = __expf(l[e] - m1);
      l[e] = p;
      den += p;
    }
    float rden = 1.0f / den;
#pragma unroll
    for (int e = 0; e < 64; ++e) lg[lane][e] = l[e] * rden;

    float e21 = __expf(m2 - m1);
    float w1 = 1.0f / (1.0f + e21);
    float w2 = e21 * w1;
    out[2 * token + 0] = w1;
    out[2 * token + 1] = w2;
    out[32768 + 2 * token + 0] = (float)i1;
    out[32768 + 2 * token + 1] = (float)i2;
  }
  __syncthreads();

  if (w == 1) {   // per-expert prob sums: lane=expert, conflict-free column sum
    float s = 0.0f;
#pragma unroll
    for (int t = 0; t < 64; ++t) s += lg[t][lane];
    atomicAdd(&acc64[lane], s);
  }
}

__global__ __launch_bounds__(64) void aux_kernel(const float* __restrict__ acc64,
                                                 float* __restrict__ out) {
  float m = acc64[threadIdx.x] * (1.0f / 16384.0f);
  float v = m * m;
#pragma unroll
  for (int off = 32; off > 0; off >>= 1) v += __shfl_down(v, off);
  if (threadIdx.x == 0) out[65536] = v * 64.0f;
}

extern "C" void kernel_launch(void* const* d_in, const int* in_sizes, int n_in,
                              void* d_out, int out_size, void* d_ws, size_t ws_size,
                              hipStream_t stream) {
  const float* x = (const float*)d_in[0];
  const float* W = (const float*)d_in[1];
  float* out = (float*)d_out;
  float* Wt = (float*)d_ws;
  float* acc64 = (float*)d_ws + 4096 * 64;

  prep_kernel<<<1024, 256, 0, stream>>>(W, Wt, acc64);
  router_main<<<256, 512, 0, stream>>>(x, Wt, out, acc64);
  aux_kernel<<<1, 64, 0, stream>>>(acc64, out);
}

// Round 3
// 182.100 us; speedup vs baseline: 2.7982x; 2.7982x over previous
//
#include <hip/hip_runtime.h>

#define DM 4096
#define NTOK 16384
#define DELTA 1e-3f
#define LIST_CAP 4096
#define LIST_OFF 16
#define ACC64_OFF (LIST_OFF + LIST_CAP * 8)   // int offset; floats live here too

typedef float f32x4 __attribute__((ext_vector_type(4)));
typedef short s16x8 __attribute__((ext_vector_type(8)));
typedef __attribute__((address_space(3))) char lds_char;
typedef const __attribute__((address_space(1))) char glb_char;

__device__ __forceinline__ void gload_lds16(const float* g, char* l) {
  __builtin_amdgcn_global_load_lds((glb_char*)g, (lds_char*)l, 16, 0, 0);
}

// split 8 f32 (two float4) into bf16-hi (truncate) and bf16-lo (truncate of residual)
__device__ __forceinline__ void split8(const f32x4 a, const f32x4 b, s16x8& h, s16x8& l) {
#pragma unroll
  for (int j = 0; j < 8; ++j) {
    float f = (j < 4) ? a[j] : b[j - 4];
    unsigned u = __builtin_bit_cast(unsigned, f);
    float hf = __builtin_bit_cast(float, u & 0xFFFF0000u);
    float lf = f - hf;
    unsigned lu = __builtin_bit_cast(unsigned, lf);
    h[j] = (short)(u >> 16);
    l[j] = (short)(lu >> 16);
  }
}

__global__ __launch_bounds__(128) void prep_kernel(int* wsi, float* wsf) {
  int t = threadIdx.x;
  if (t == 0) wsi[0] = 0;                     // fixup-list counter
  if (t < 64) wsf[ACC64_OFF + t] = 0.0f;      // per-expert prob sums
}

__global__ __launch_bounds__(512, 4) void router_main(const float* __restrict__ x,
                                                      const float* __restrict__ W,
                                                      float* __restrict__ out,
                                                      int* __restrict__ wsi,
                                                      float* __restrict__ wsf) {
  __shared__ char smem[16384];                // 2 x 8KB staging bufs; reused as lg[32][65]
  const int tid = threadIdx.x, lane = tid & 63, w = tid >> 6;
  const int msub = w & 1, nsub = (w >> 1) & 1, kh = w >> 2;
  const int tb = blockIdx.x * 32;

  // ---- staging: slot = [row sr][col lane&15], global chunk pre-XOR'd (m104/m173) ----
  const int sr = (w << 2) + (lane >> 4);                  // 0..31
  const int sc = (lane & 15) ^ (sr & 7);                  // source chunk
  const float* gx = x + (size_t)(tb + sr) * DM + sc * 4;
  char* lds_wbase = smem + w * 1024;                      // +buf*8192; HW adds lane*16

  // ---- A-frag LDS addresses (same XOR on read side) ----
  const int trow = msub * 16 + (lane & 15);
  const int oct = lane >> 4;
  const int c0 = kh * 8 + oct * 2;
  const int aoff0 = trow * 256 + (((c0)     ^ (trow & 7)) << 4);
  const int aoff1 = trow * 256 + (((c0 + 1) ^ (trow & 7)) << 4);

  // ---- B pointers: 2 expert groups of 16, same k-octet convention as A ----
  const int e0 = (nsub * 2 + 0) * 16 + (lane & 15);
  const int e1 = (nsub * 2 + 1) * 16 + (lane & 15);
  const float* pB0 = W + (size_t)e0 * DM + kh * 32 + oct * 8;
  const float* pB1 = W + (size_t)e1 * DM + kh * 32 + oct * 8;

  f32x4 acc0 = {0.f, 0.f, 0.f, 0.f}, acc1 = {0.f, 0.f, 0.f, 0.f};

  gload_lds16(gx, lds_wbase);                 // prologue: stage T=0 into buf0

  for (int T = 0; T < 64; ++T) {
    __syncthreads();                          // buf(T&1) staged & drained
    const char* abase = smem + (T & 1) * 8192;
    f32x4 xa = *(const f32x4*)(abase + aoff0);
    f32x4 xb = *(const f32x4*)(abase + aoff1);
    const float* b0 = pB0 + T * 64;
    const float* b1 = pB1 + T * 64;
    f32x4 wa0 = *(const f32x4*)(b0), wa1 = *(const f32x4*)(b0 + 4);
    f32x4 wb0 = *(const f32x4*)(b1), wb1 = *(const f32x4*)(b1 + 4);

    s16x8 ah, al, bh0, bl0, bh1, bl1;
    split8(xa, xb, ah, al);                   // consumes lgkm (A)
    split8(wa0, wa1, bh0, bl0);               // consumes vmcnt (B) ...
    split8(wb0, wb1, bh1, bl1);               // ... so stage below stays newest
    if (T < 63)                               // issue next tile AFTER all vm consumers
      gload_lds16(gx + (T + 1) * 64, lds_wbase + ((T + 1) & 1) * 8192);

    acc0 = __builtin_amdgcn_mfma_f32_16x16x32_bf16(ah, bh0, acc0, 0, 0, 0);
    acc0 = __builtin_amdgcn_mfma_f32_16x16x32_bf16(al, bh0, acc0, 0, 0, 0);
    acc0 = __builtin_amdgcn_mfma_f32_16x16x32_bf16(ah, bl0, acc0, 0, 0, 0);
    acc0 = __builtin_amdgcn_mfma_f32_16x16x32_bf16(al, bl0, acc0, 0, 0, 0);
    acc1 = __builtin_amdgcn_mfma_f32_16x16x32_bf16(ah, bh1, acc1, 0, 0, 0);
    acc1 = __builtin_amdgcn_mfma_f32_16x16x32_bf16(al, bh1, acc1, 0, 0, 0);
    acc1 = __builtin_amdgcn_mfma_f32_16x16x32_bf16(ah, bl1, acc1, 0, 0, 0);
    acc1 = __builtin_amdgcn_mfma_f32_16x16x32_bf16(al, bl1, acc1, 0, 0, 0);
  }

  // ---- epilogue: smem becomes lg[32][65] ----
  __syncthreads();
  float (*lg)[65] = (float (*)[65])smem;
  float* lgf = (float*)smem;
  for (int i = tid; i < 32 * 65; i += 512) lgf[i] = 0.0f;
  __syncthreads();
  {
    // C layout (m89): col=lane&15 (expert), row=(lane>>4)*4+reg (token)
    const int et = (lane & 15);
    const int tt = msub * 16 + (lane >> 4) * 4;
#pragma unroll
    for (int q = 0; q < 4; ++q) {
      atomicAdd(&lg[tt + q][(nsub * 2 + 0) * 16 + et], acc0[q]);
      atomicAdd(&lg[tt + q][(nsub * 2 + 1) * 16 + et], acc1[q]);
    }
  }
  __syncthreads();

  if (w == 0 && lane < 32) {                  // lane = token within block
    const int token = tb + lane;
    float l[64];
    float m1 = -3.4e38f, m2 = -3.4e38f, m3 = -3.4e38f, m4 = -3.4e38f;
    int i1 = 0, i2 = 0, i3 = 0, i4 = 0;
#pragma unroll
    for (int e = 0; e < 64; ++e) {            // ascending e + strict > = lax.top_k order
      float v = lg[lane][e];
      l[e] = v;
      if (v > m1)      { m4=m3;i4=i3; m3=m2;i3=i2; m2=m1;i2=i1; m1=v;i1=e; }
      else if (v > m2) { m4=m3;i4=i3; m3=m2;i3=i2; m2=v;i2=e; }
      else if (v > m3) { m4=m3;i4=i3; m3=v;i3=e; }
      else if (v > m4) { m4=v;i4=e; }
    }
    float den = 0.0f;
#pragma unroll
    for (int e = 0; e < 64; ++e) { float p = __expf(l[e] - m1); l[e] = p; den += p; }
    float rden = 1.0f / den;
#pragma unroll
    for (int e = 0; e < 64; ++e) lg[lane][e] = l[e] * rden;   // probs for aux

    float e21 = __expf(m2 - m1);
    float w1 = 1.0f / (1.0f + e21);
    float w2 = e21 * w1;
    out[2 * token + 0] = w1;
    out[2 * token + 1] = w2;
    out[32768 + 2 * token + 0] = (float)i1;
    out[32768 + 2 * token + 1] = (float)i2;

    if ((m1 - m2 < DELTA) || (m2 - m3 < DELTA)) {             // ambiguous: exact re-rank later
      int idx = atomicAdd(wsi, 1);
      if (idx < LIST_CAP) {
        int* ent = wsi + LIST_OFF + idx * 8;
        ent[0] = token; ent[1] = i1; ent[2] = i2; ent[3] = i3; ent[4] = i4;
      }
    }
  }
  __syncthreads();

  if (w == 1) {                               // lane = expert: column sums over 32 tokens
    float s = 0.0f;
#pragma unroll
    for (int t = 0; t < 32; ++t) s += lg[t][lane];
    atomicAdd(&wsf[ACC64_OFF + lane], s);
  }
}

__global__ __launch_bounds__(64) void aux_kernel(const float* __restrict__ wsf,
                                                 float* __restrict__ out) {
  float m = wsf[ACC64_OFF + threadIdx.x] * (1.0f / 16384.0f);
  float v = m * m;
#pragma unroll
  for (int off = 32; off > 0; off >>= 1) v += __shfl_down(v, off);
  if (threadIdx.x == 0) out[65536] = v * 64.0f;
}

__global__ __launch_bounds__(256) void fixup_kernel(const float* __restrict__ x,
                                                    const float* __restrict__ W,
                                                    float* __restrict__ out,
                                                    const int* __restrict__ wsi) {
  int count = wsi[0]; if (count > LIST_CAP) count = LIST_CAP;
  const int wgid = blockIdx.x * 4 + (threadIdx.x >> 6);
  const int lane = threadIdx.x & 63;
  for (int idx = wgid; idx < count; idx += 256) {
    const int* ent = wsi + LIST_OFF + idx * 8;
    const int t = ent[0];
    int e[4] = {ent[1], ent[2], ent[3], ent[4]};
    float s0 = 0, s1 = 0, s2 = 0, s3 = 0;
    const f32x4* x4 = (const f32x4*)(x + (size_t)t * DM);
    const f32x4* W4 = (const f32x4*)W;
#pragma unroll 4
    for (int st = 0; st < 16; ++st) {
      f32x4 xv = x4[st * 64 + lane];
      f32x4 v0 = W4[(size_t)e[0] * 1024 + st * 64 + lane];
      f32x4 v1 = W4[(size_t)e[1] * 1024 + st * 64 + lane];
      f32x4 v2 = W4[(size_t)e[2] * 1024 + st * 64 + lane];
      f32x4 v3 = W4[(size_t)e[3] * 1024 + st * 64 + lane];
#pragma unroll
      for (int j = 0; j < 4; ++j) {
        s0 = fmaf(xv[j], v0[j], s0);
        s1 = fmaf(xv[j], v1[j], s1);
        s2 = fmaf(xv[j], v2[j], s2);
        s3 = fmaf(xv[j], v3[j], s3);
      }
    }
#pragma unroll
    for (int off = 32; off > 0; off >>= 1) {
      s0 += __shfl_down(s0, off); s1 += __shfl_down(s1, off);
      s2 += __shfl_down(s2, off); s3 += __shfl_down(s3, off);
    }
    if (lane == 0) {
      float v[4] = {s0, s1, s2, s3};
      int ord[4] = {0, 1, 2, 3};               // sort candidates by expert index asc
      for (int a = 0; a < 3; ++a)
        for (int b = 0; b < 3 - a; ++b)
          if (e[ord[b]] > e[ord[b + 1]]) { int tmp = ord[b]; ord[b] = ord[b + 1]; ord[b + 1] = tmp; }
      float m1 = -3.4e38f, m2 = -3.4e38f; int i1 = -1, i2 = -1;
      for (int a = 0; a < 4; ++a) {            // ascending index + strict > = np tie-break
        float vv = v[ord[a]]; int ee = e[ord[a]];
        if (vv > m1) { m2 = m1; i2 = i1; m1 = vv; i1 = ee; }
        else if (vv > m2) { m2 = vv; i2 = ee; }
      }
      float e21 = __expf(m2 - m1);
      float w1 = 1.0f / (1.0f + e21);
      float w2 = e21 * w1;
      out[2 * t + 0] = w1;
      out[2 * t + 1] = w2;
      out[32768 + 2 * t + 0] = (float)i1;
      out[32768 + 2 * t + 1] = (float)i2;
    }
  }
}

extern "C" void kernel_launch(void* const* d_in, const int* in_sizes, int n_in,
                              void* d_out, int out_size, void* d_ws, size_t ws_size,
                              hipStream_t stream) {
  const float* x = (const float*)d_in[0];
  const float* W = (const float*)d_in[1];
  float* out = (float*)d_out;
  int* wsi = (int*)d_ws;
  float* wsf = (float*)d_ws;

  prep_kernel<<<1, 128, 0, stream>>>(wsi, wsf);
  router_main<<<512, 512, 0, stream>>>(x, W, out, wsi, wsf);
  aux_kernel<<<1, 64, 0, stream>>>(wsf, out);
  fixup_kernel<<<64, 256, 0, stream>>>(x, W, out, wsi);
}